// Round 6
// baseline (260.110 us; speedup 1.0000x reference)
//
#include <hip/hip_runtime.h>
#include <float.h>

// Grid dims from the reference
#define BDIM 4
#define ZDIM 6
#define YDIM 200
#define XDIM 176
#define CDIM 64
#define KSLOTS (BDIM * ZDIM * YDIM * XDIM)  // 844800
#define BINV 64                              // voxels per bin
#define NBIN (KSLOTS / BINV)                 // 13200
#define NBIN2 (2 * NBIN)                     // 26400
#define SCAN_T 1024
#define EPT 26                               // 1024*26 = 26624 >= 26400

typedef float f32x4 __attribute__((ext_vector_type(4)));

__device__ __forceinline__ int voxel_key4(const int4 c) {
    return ((c.x * ZDIM + c.y) * YDIM + c.z) * XDIM + c.w;
}
// monotonic float<->uint order encoding; 0u = "empty" sentinel (below all reals)
__device__ __forceinline__ unsigned ord_enc(float f) {
    unsigned u = __float_as_uint(f);
    return (u & 0x80000000u) ? ~u : (u | 0x80000000u);
}
__device__ __forceinline__ float ord_dec(unsigned u) {
    return (u & 0x80000000u) ? __uint_as_float(u & 0x7FFFFFFFu)
                             : __uint_as_float(~u);
}

// ---------------- CSR build at BIN granularity ----------------

// Histogram both coord sets into pos[NBIN2] (set2 at offset NBIN).
__global__ void hist2_kernel(const int* __restrict__ c1, int n1,
                             const int* __restrict__ c2, int n2,
                             int* __restrict__ pos) {
    int i = blockIdx.x * blockDim.x + threadIdx.x;
    if (i < n1) {
        int4 cc = *reinterpret_cast<const int4*>(c1 + (long long)i * 4);
        atomicAdd(&pos[voxel_key4(cc) >> 6], 1);
    } else if (i < n1 + n2) {
        int j = i - n1;
        int4 cc = *reinterpret_cast<const int4*>(c2 + (long long)j * 4);
        atomicAdd(&pos[NBIN + (voxel_key4(cc) >> 6)], 1);
    }
}

// Single-block in-place exclusive scan over pos[NBIN2] (each thread owns a
// disjoint 26-elem chunk: regs -> wave shfl scan -> LDS wave combine).
__global__ __launch_bounds__(SCAN_T) void scan_kernel(int* __restrict__ pos) {
    __shared__ int wsum[SCAN_T / 64];
    int t = threadIdx.x;
    int base = t * EPT;
    int v[EPT];
    int s = 0;
    #pragma unroll
    for (int i = 0; i < EPT; ++i) {
        v[i] = (base + i < NBIN2) ? pos[base + i] : 0;
        s += v[i];
    }
    int lane = t & 63, wid = t >> 6;
    int x = s;
    #pragma unroll
    for (int off = 1; off < 64; off <<= 1) {
        int y = __shfl_up(x, off, 64);
        if (lane >= off) x += y;
    }
    if (lane == 63) wsum[wid] = x;
    __syncthreads();
    if (t < SCAN_T / 64) {
        int w = wsum[t];
        int xx = w;
        #pragma unroll
        for (int off = 1; off < SCAN_T / 64; off <<= 1) {
            int y = __shfl_up(xx, off, SCAN_T / 64);
            if (t >= off) xx += y;
        }
        wsum[t] = xx - w;  // exclusive wave offset
    }
    __syncthreads();
    int run = wsum[wid] + x - s;  // exclusive prefix of this chunk
    #pragma unroll
    for (int i = 0; i < EPT; ++i) {
        if (base + i < NBIN2) pos[base + i] = run;
        run += v[i];
    }
}

// Scatter packed records (point<<6 | local_voxel); pos[] doubles as cursor,
// so afterwards pos[g] == run END (begin(g) = g==0 ? 0 : pos[g-1]).
__global__ void scatter2_kernel(const int* __restrict__ c1, int n1,
                                const int* __restrict__ c2, int n2,
                                int* __restrict__ pos, int* __restrict__ recs) {
    int i = blockIdx.x * blockDim.x + threadIdx.x;
    if (i < n1) {
        int4 cc = *reinterpret_cast<const int4*>(c1 + (long long)i * 4);
        int key = voxel_key4(cc);
        int slot = atomicAdd(&pos[key >> 6], 1);
        recs[slot] = (i << 6) | (key & 63);
    } else if (i < n1 + n2) {
        int j = i - n1;
        int4 cc = *reinterpret_cast<const int4*>(c2 + (long long)j * 4);
        int key = voxel_key4(cc);
        int slot = atomicAdd(&pos[NBIN + (key >> 6)], 1);
        recs[slot] = (j << 6) | (key & 63);
    }
}

// ---------------- fused bin-local accumulate ----------------
// One block per bin (64 voxels x 64 ch = 16KB LDS tile). 8 groups of 32
// lanes; each group streams points 2-at-a-time: row read = 2 coalesced 128B
// segments (words lane, lane+32), accumulate via LDS atomics (2 lanes/bank =
// conflict-free). max-encode phase -> in-place decode -> f32 add phase ->
// contiguous nontemporal writeout.
__global__ __launch_bounds__(256) void fuse_kernel(
        const float* __restrict__ f1, const float* __restrict__ f2,
        const int* __restrict__ recs, const int* __restrict__ pos,
        float* __restrict__ out) {
    __shared__ unsigned acc[BINV * CDIM];  // 16KB; uint (encoded) then float
    int b = blockIdx.x;
    int t = threadIdx.x;
    int b1 = (b == 0) ? 0 : pos[b - 1];
    int e1 = pos[b];
    int b2 = pos[NBIN + b - 1];   // b==0 -> pos[NBIN-1] == n1 (end of set1)
    int e2 = pos[NBIN + b];

    #pragma unroll
    for (int k = 0; k < 16; ++k) acc[t + k * 256] = 0u;  // 0 = empty sentinel
    __syncthreads();

    int lane = t & 31;   // channel lane (covers ch lane and lane+32)
    int grp  = t >> 5;   // 8 point-groups

    // ---- set2: scatter-max into LDS ----
    int cnt2 = e2 - b2;
    if (cnt2 > 0) {
        int rounds = (cnt2 + 15) >> 4;
        int last = e2 - 1;
        for (int r = 0; r < rounds; ++r) {
            int j0 = b2 + r * 16 + grp;
            int j1 = j0 + 8;
            int rec0 = recs[min(j0, last)];
            int rec1 = recs[min(j1, last)];
            const float* p0 = f2 + (long long)(rec0 >> 6) * CDIM;
            const float* p1 = f2 + (long long)(rec1 >> 6) * CDIM;
            float a0 = p0[lane], a1 = p0[lane + 32];
            float c0 = p1[lane], c1 = p1[lane + 32];
            int lv0 = (rec0 & 63) * CDIM;
            int lv1 = (rec1 & 63) * CDIM;
            if (j0 < e2) {
                atomicMax(&acc[lv0 + lane],      ord_enc(a0));
                atomicMax(&acc[lv0 + lane + 32], ord_enc(a1));
            }
            if (j1 < e2) {
                atomicMax(&acc[lv1 + lane],      ord_enc(c0));
                atomicMax(&acc[lv1 + lane + 32], ord_enc(c1));
            }
        }
    }
    __syncthreads();

    // in-place decode: encoded uint -> float bits (0u -> 0.0f)
    #pragma unroll
    for (int k = 0; k < 16; ++k) {
        int w = t + k * 256;
        unsigned u = acc[w];
        float f = (u == 0u) ? 0.f : ord_dec(u);
        acc[w] = __float_as_uint(f);
    }
    __syncthreads();

    float* facc = (float*)acc;

    // ---- set1: scatter-add onto decoded max (fused = max + sum) ----
    int cnt1 = e1 - b1;
    if (cnt1 > 0) {
        int rounds = (cnt1 + 15) >> 4;
        int last = e1 - 1;
        for (int r = 0; r < rounds; ++r) {
            int j0 = b1 + r * 16 + grp;
            int j1 = j0 + 8;
            int rec0 = recs[min(j0, last)];
            int rec1 = recs[min(j1, last)];
            const float* p0 = f1 + (long long)(rec0 >> 6) * CDIM;
            const float* p1 = f1 + (long long)(rec1 >> 6) * CDIM;
            float a0 = p0[lane], a1 = p0[lane + 32];
            float c0 = p1[lane], c1 = p1[lane + 32];
            int lv0 = (rec0 & 63) * CDIM;
            int lv1 = (rec1 & 63) * CDIM;
            if (j0 < e1) {
                atomicAdd(&facc[lv0 + lane],      a0);
                atomicAdd(&facc[lv0 + lane + 32], a1);
            }
            if (j1 < e1) {
                atomicAdd(&facc[lv1 + lane],      c0);
                atomicAdd(&facc[lv1 + lane + 32], c1);
            }
        }
    }
    __syncthreads();

    // ---- writeout: contiguous 16KB, full-line nt stores ----
    float* ob = out + (long long)b * (BINV * CDIM);
    #pragma unroll
    for (int k = 0; k < 4; ++k) {
        int w = k * 1024 + t * 4;
        f32x4 val = *(f32x4*)&facc[w];
        __builtin_nontemporal_store(val, (f32x4*)(ob + w));
    }
}

// ---------------- fallback (atomic path, used only if ws too small) ----------

__global__ void fb_scatter_max(const float* __restrict__ feats, const int* __restrict__ coords,
                               unsigned* __restrict__ out, int npts) {
    long long i = (long long)blockIdx.x * blockDim.x + threadIdx.x;
    if (i >= (long long)npts * (CDIM / 4)) return;
    int pt = (int)(i >> 4), c4 = (int)(i & 15);
    int4 cc = *reinterpret_cast<const int4*>(coords + (long long)pt * 4);
    int key = voxel_key4(cc);
    float4 f = *reinterpret_cast<const float4*>(feats + (long long)pt * CDIM + c4 * 4);
    unsigned* dst = out + (long long)key * CDIM + c4 * 4;
    atomicMax(dst + 0, ord_enc(f.x));
    atomicMax(dst + 1, ord_enc(f.y));
    atomicMax(dst + 2, ord_enc(f.z));
    atomicMax(dst + 3, ord_enc(f.w));
}
__global__ void fb_decode(unsigned* __restrict__ buf, long long n4) {
    long long i = (long long)blockIdx.x * blockDim.x + threadIdx.x;
    if (i >= n4) return;
    uint4 u = reinterpret_cast<const uint4*>(buf)[i];
    float4 f;
    f.x = (u.x == 0u) ? 0.f : ord_dec(u.x);
    f.y = (u.y == 0u) ? 0.f : ord_dec(u.y);
    f.z = (u.z == 0u) ? 0.f : ord_dec(u.z);
    f.w = (u.w == 0u) ? 0.f : ord_dec(u.w);
    reinterpret_cast<float4*>(buf)[i] = f;
}
__global__ void fb_scatter_add(const float* __restrict__ feats, const int* __restrict__ coords,
                               float* __restrict__ out, int npts) {
    long long i = (long long)blockIdx.x * blockDim.x + threadIdx.x;
    if (i >= (long long)npts * (CDIM / 4)) return;
    int pt = (int)(i >> 4), c4 = (int)(i & 15);
    int4 cc = *reinterpret_cast<const int4*>(coords + (long long)pt * 4);
    int key = voxel_key4(cc);
    float4 f = *reinterpret_cast<const float4*>(feats + (long long)pt * CDIM + c4 * 4);
    float* dst = out + (long long)key * CDIM + c4 * 4;
    atomicAdd(dst + 0, f.x); atomicAdd(dst + 1, f.y);
    atomicAdd(dst + 2, f.z); atomicAdd(dst + 3, f.w);
}

extern "C" void kernel_launch(void* const* d_in, const int* in_sizes, int n_in,
                              void* d_out, int out_size, void* d_ws, size_t ws_size,
                              hipStream_t stream) {
    const float* feats1 = (const float*)d_in[0];
    const int*   coords1 = (const int*)d_in[1];
    const float* feats2 = (const float*)d_in[2];
    const int*   coords2 = (const int*)d_in[3];
    float* out = (float*)d_out;

    const int n1 = in_sizes[1] / 4;
    const int n2 = in_sizes[3] / 4;
    const int n12 = n1 + n2;
    const long long kc = (long long)KSLOTS * CDIM;

    const size_t needed = ((size_t)NBIN2 + n12) * sizeof(int);
    if (ws_size < needed) {
        hipMemsetAsync(d_out, 0, kc * sizeof(float), stream);
        long long t2 = (long long)n2 * (CDIM / 4);
        fb_scatter_max<<<(int)((t2 + 255) / 256), 256, 0, stream>>>(feats2, coords2,
                                                                    (unsigned*)out, n2);
        long long q = kc / 4;
        fb_decode<<<(int)((q + 255) / 256), 256, 0, stream>>>((unsigned*)out, q);
        long long t1 = (long long)n1 * (CDIM / 4);
        fb_scatter_add<<<(int)((t1 + 255) / 256), 256, 0, stream>>>(feats1, coords1, out, n1);
        return;
    }

    // ws layout: pos[NBIN2] (hist counts -> scan -> cursor/rowptr) | recs[n12]
    int* pos  = (int*)d_ws;
    int* recs = pos + NBIN2;

    hipMemsetAsync(pos, 0, (size_t)NBIN2 * sizeof(int), stream);

    int nb12 = (n12 + 255) / 256;
    hist2_kernel<<<nb12, 256, 0, stream>>>(coords1, n1, coords2, n2, pos);
    scan_kernel<<<1, SCAN_T, 0, stream>>>(pos);
    scatter2_kernel<<<nb12, 256, 0, stream>>>(coords1, n1, coords2, n2, pos, recs);
    fuse_kernel<<<NBIN, 256, 0, stream>>>(feats1, feats2, recs, pos, out);
}

// Round 7
// 241.887 us; speedup vs baseline: 1.0753x; 1.0753x over previous
//
#include <hip/hip_runtime.h>
#include <float.h>

// Grid dims from the reference
#define BDIM 4
#define ZDIM 6
#define YDIM 200
#define XDIM 176
#define CDIM 64
#define KSLOTS (BDIM * ZDIM * YDIM * XDIM)  // 844800
#define BINV 64                              // voxels per bin
#define NBIN (KSLOTS / BINV)                 // 13200
#define NBIN2 (2 * NBIN)                     // 26400
#define SCAN_T 1024
#define EPT 26                               // 1024*26 = 26624 >= 26400
#define CAP1 128                             // staged recs cap, set1 (avg ~15)
#define CAP2 384                             // staged recs cap, set2 (avg ~61)

typedef float f32x4 __attribute__((ext_vector_type(4)));

__device__ __forceinline__ int voxel_key4(const int4 c) {
    return ((c.x * ZDIM + c.y) * YDIM + c.z) * XDIM + c.w;
}
// monotonic float<->uint order encoding; 0u = "empty" sentinel (below all reals)
__device__ __forceinline__ unsigned ord_enc(float f) {
    unsigned u = __float_as_uint(f);
    return (u & 0x80000000u) ? ~u : (u | 0x80000000u);
}
__device__ __forceinline__ float ord_dec(unsigned u) {
    return (u & 0x80000000u) ? __uint_as_float(u & 0x7FFFFFFFu)
                             : __uint_as_float(~u);
}

// ---------------- CSR build at BIN granularity ----------------

__global__ void hist2_kernel(const int* __restrict__ c1, int n1,
                             const int* __restrict__ c2, int n2,
                             int* __restrict__ pos) {
    int i = blockIdx.x * blockDim.x + threadIdx.x;
    if (i < n1) {
        int4 cc = *reinterpret_cast<const int4*>(c1 + (long long)i * 4);
        atomicAdd(&pos[voxel_key4(cc) >> 6], 1);
    } else if (i < n1 + n2) {
        int j = i - n1;
        int4 cc = *reinterpret_cast<const int4*>(c2 + (long long)j * 4);
        atomicAdd(&pos[NBIN + (voxel_key4(cc) >> 6)], 1);
    }
}

// Single-block in-place exclusive scan over pos[NBIN2].
__global__ __launch_bounds__(SCAN_T) void scan_kernel(int* __restrict__ pos) {
    __shared__ int wsum[SCAN_T / 64];
    int t = threadIdx.x;
    int base = t * EPT;
    int v[EPT];
    int s = 0;
    #pragma unroll
    for (int i = 0; i < EPT; ++i) {
        v[i] = (base + i < NBIN2) ? pos[base + i] : 0;
        s += v[i];
    }
    int lane = t & 63, wid = t >> 6;
    int x = s;
    #pragma unroll
    for (int off = 1; off < 64; off <<= 1) {
        int y = __shfl_up(x, off, 64);
        if (lane >= off) x += y;
    }
    if (lane == 63) wsum[wid] = x;
    __syncthreads();
    if (t < SCAN_T / 64) {
        int w = wsum[t];
        int xx = w;
        #pragma unroll
        for (int off = 1; off < SCAN_T / 64; off <<= 1) {
            int y = __shfl_up(xx, off, SCAN_T / 64);
            if (t >= off) xx += y;
        }
        wsum[t] = xx - w;
    }
    __syncthreads();
    int run = wsum[wid] + x - s;
    #pragma unroll
    for (int i = 0; i < EPT; ++i) {
        if (base + i < NBIN2) pos[base + i] = run;
        run += v[i];
    }
}

// Scatter packed records (point<<6 | local_voxel); pos[] doubles as cursor,
// so afterwards pos[g] == run END (begin(g) = g==0 ? 0 : pos[g-1]).
__global__ void scatter2_kernel(const int* __restrict__ c1, int n1,
                                const int* __restrict__ c2, int n2,
                                int* __restrict__ pos, int* __restrict__ recs) {
    int i = blockIdx.x * blockDim.x + threadIdx.x;
    if (i < n1) {
        int4 cc = *reinterpret_cast<const int4*>(c1 + (long long)i * 4);
        int key = voxel_key4(cc);
        int slot = atomicAdd(&pos[key >> 6], 1);
        recs[slot] = (i << 6) | (key & 63);
    } else if (i < n1 + n2) {
        int j = i - n1;
        int4 cc = *reinterpret_cast<const int4*>(c2 + (long long)j * 4);
        int key = voxel_key4(cc);
        int slot = atomicAdd(&pos[NBIN + (key >> 6)], 1);
        recs[slot] = (j << 6) | (key & 63);
    }
}

// ---------------- fused bin-local accumulate (recs staged in LDS) ----------
// One block per bin (64 voxels x 64 ch = 16KB tile). Stage the bin's record
// lists in LDS, then each of 8 groups x 32 lanes issues 8 INDEPENDENT global
// dword loads per iteration (4 points x 2 half-rows, clamped) before any
// LDS atomic -> ~2KB/wave in flight instead of ~512B.
__global__ __launch_bounds__(256) void fuse_kernel(
        const float* __restrict__ f1, const float* __restrict__ f2,
        const int* __restrict__ recs, const int* __restrict__ pos,
        float* __restrict__ out) {
    __shared__ unsigned acc[BINV * CDIM];   // 16 KB (encoded uints, then floats)
    __shared__ int rl1[CAP1];
    __shared__ int rl2[CAP2];
    int b = blockIdx.x;
    int t = threadIdx.x;
    int e1 = pos[b];
    int b1 = (b == 0) ? 0 : pos[b - 1];
    int e2 = pos[NBIN + b];
    int b2 = pos[NBIN + b - 1];   // b==0 -> pos[NBIN-1] == n1 (start of set2)
    int cnt1 = e1 - b1, cnt2 = e2 - b2;
    int ns1 = min(cnt1, CAP1), ns2 = min(cnt2, CAP2);

    #pragma unroll
    for (int k = 0; k < 16; ++k) acc[t + k * 256] = 0u;  // 0 = empty sentinel
    for (int i = t; i < ns2; i += 256) rl2[i] = recs[b2 + i];
    for (int i = t; i < ns1; i += 256) rl1[i] = recs[b1 + i];
    __syncthreads();

    int lane = t & 31;   // channel lane (covers ch lane and lane+32)
    int grp  = t >> 5;   // 8 point-groups

    // ---- set2: scatter-max into LDS, 4 points/group/iter ----
    for (int base = 0; base < ns2; base += 32) {
        int i0 = base + grp * 4;
        int last = ns2 - 1;
        int rr[4]; float lo[4], hi[4];
        #pragma unroll
        for (int k = 0; k < 4; ++k) rr[k] = rl2[min(i0 + k, last)];
        #pragma unroll
        for (int k = 0; k < 4; ++k) {
            const float* p = f2 + (long long)(rr[k] >> 6) * CDIM;
            lo[k] = p[lane];
            hi[k] = p[lane + 32];
        }
        #pragma unroll
        for (int k = 0; k < 4; ++k) {
            if (i0 + k < ns2) {
                int lv = (rr[k] & 63) * CDIM;
                atomicMax(&acc[lv + lane],      ord_enc(lo[k]));
                atomicMax(&acc[lv + lane + 32], ord_enc(hi[k]));
            }
        }
    }
    // overflow tail (recs beyond CAP2), statistically near-never
    for (int i = ns2 + grp; i < cnt2; i += 8) {
        int rec = recs[b2 + i];
        const float* p = f2 + (long long)(rec >> 6) * CDIM;
        float lo = p[lane], hi = p[lane + 32];
        int lv = (rec & 63) * CDIM;
        atomicMax(&acc[lv + lane],      ord_enc(lo));
        atomicMax(&acc[lv + lane + 32], ord_enc(hi));
    }
    __syncthreads();

    // in-place decode: encoded uint -> float bits (0u -> 0.0f)
    #pragma unroll
    for (int k = 0; k < 16; ++k) {
        int w = t + k * 256;
        unsigned u = acc[w];
        float f = (u == 0u) ? 0.f : ord_dec(u);
        acc[w] = __float_as_uint(f);
    }
    __syncthreads();

    float* facc = (float*)acc;

    // ---- set1: scatter-add onto decoded max, 2 points/group/iter ----
    for (int base = 0; base < ns1; base += 16) {
        int i0 = base + grp * 2;
        int last = ns1 - 1;
        int rr[2]; float lo[2], hi[2];
        #pragma unroll
        for (int k = 0; k < 2; ++k) rr[k] = rl1[min(i0 + k, last)];
        #pragma unroll
        for (int k = 0; k < 2; ++k) {
            const float* p = f1 + (long long)(rr[k] >> 6) * CDIM;
            lo[k] = p[lane];
            hi[k] = p[lane + 32];
        }
        #pragma unroll
        for (int k = 0; k < 2; ++k) {
            if (i0 + k < ns1) {
                int lv = (rr[k] & 63) * CDIM;
                atomicAdd(&facc[lv + lane],      lo[k]);
                atomicAdd(&facc[lv + lane + 32], hi[k]);
            }
        }
    }
    for (int i = ns1 + grp; i < cnt1; i += 8) {
        int rec = recs[b1 + i];
        const float* p = f1 + (long long)(rec >> 6) * CDIM;
        float lo = p[lane], hi = p[lane + 32];
        int lv = (rec & 63) * CDIM;
        atomicAdd(&facc[lv + lane],      lo);
        atomicAdd(&facc[lv + lane + 32], hi);
    }
    __syncthreads();

    // ---- writeout: contiguous 16KB, full-line nt stores ----
    float* ob = out + (long long)b * (BINV * CDIM);
    #pragma unroll
    for (int k = 0; k < 4; ++k) {
        int w = k * 1024 + t * 4;
        f32x4 val = *(f32x4*)&facc[w];
        __builtin_nontemporal_store(val, (f32x4*)(ob + w));
    }
}

// ---------------- fallback (atomic path, used only if ws too small) ----------

__global__ void fb_scatter_max(const float* __restrict__ feats, const int* __restrict__ coords,
                               unsigned* __restrict__ out, int npts) {
    long long i = (long long)blockIdx.x * blockDim.x + threadIdx.x;
    if (i >= (long long)npts * (CDIM / 4)) return;
    int pt = (int)(i >> 4), c4 = (int)(i & 15);
    int4 cc = *reinterpret_cast<const int4*>(coords + (long long)pt * 4);
    int key = voxel_key4(cc);
    float4 f = *reinterpret_cast<const float4*>(feats + (long long)pt * CDIM + c4 * 4);
    unsigned* dst = out + (long long)key * CDIM + c4 * 4;
    atomicMax(dst + 0, ord_enc(f.x));
    atomicMax(dst + 1, ord_enc(f.y));
    atomicMax(dst + 2, ord_enc(f.z));
    atomicMax(dst + 3, ord_enc(f.w));
}
__global__ void fb_decode(unsigned* __restrict__ buf, long long n4) {
    long long i = (long long)blockIdx.x * blockDim.x + threadIdx.x;
    if (i >= n4) return;
    uint4 u = reinterpret_cast<const uint4*>(buf)[i];
    float4 f;
    f.x = (u.x == 0u) ? 0.f : ord_dec(u.x);
    f.y = (u.y == 0u) ? 0.f : ord_dec(u.y);
    f.z = (u.z == 0u) ? 0.f : ord_dec(u.z);
    f.w = (u.w == 0u) ? 0.f : ord_dec(u.w);
    reinterpret_cast<float4*>(buf)[i] = f;
}
__global__ void fb_scatter_add(const float* __restrict__ feats, const int* __restrict__ coords,
                               float* __restrict__ out, int npts) {
    long long i = (long long)blockIdx.x * blockDim.x + threadIdx.x;
    if (i >= (long long)npts * (CDIM / 4)) return;
    int pt = (int)(i >> 4), c4 = (int)(i & 15);
    int4 cc = *reinterpret_cast<const int4*>(coords + (long long)pt * 4);
    int key = voxel_key4(cc);
    float4 f = *reinterpret_cast<const float4*>(feats + (long long)pt * CDIM + c4 * 4);
    float* dst = out + (long long)key * CDIM + c4 * 4;
    atomicAdd(dst + 0, f.x); atomicAdd(dst + 1, f.y);
    atomicAdd(dst + 2, f.z); atomicAdd(dst + 3, f.w);
}

extern "C" void kernel_launch(void* const* d_in, const int* in_sizes, int n_in,
                              void* d_out, int out_size, void* d_ws, size_t ws_size,
                              hipStream_t stream) {
    const float* feats1 = (const float*)d_in[0];
    const int*   coords1 = (const int*)d_in[1];
    const float* feats2 = (const float*)d_in[2];
    const int*   coords2 = (const int*)d_in[3];
    float* out = (float*)d_out;

    const int n1 = in_sizes[1] / 4;
    const int n2 = in_sizes[3] / 4;
    const int n12 = n1 + n2;
    const long long kc = (long long)KSLOTS * CDIM;

    const size_t needed = ((size_t)NBIN2 + n12) * sizeof(int);
    if (ws_size < needed) {
        hipMemsetAsync(d_out, 0, kc * sizeof(float), stream);
        long long t2 = (long long)n2 * (CDIM / 4);
        fb_scatter_max<<<(int)((t2 + 255) / 256), 256, 0, stream>>>(feats2, coords2,
                                                                    (unsigned*)out, n2);
        long long q = kc / 4;
        fb_decode<<<(int)((q + 255) / 256), 256, 0, stream>>>((unsigned*)out, q);
        long long t1 = (long long)n1 * (CDIM / 4);
        fb_scatter_add<<<(int)((t1 + 255) / 256), 256, 0, stream>>>(feats1, coords1, out, n1);
        return;
    }

    // ws layout: pos[NBIN2] (hist counts -> scan -> cursor/rowptr) | recs[n12]
    int* pos  = (int*)d_ws;
    int* recs = pos + NBIN2;

    hipMemsetAsync(pos, 0, (size_t)NBIN2 * sizeof(int), stream);

    int nb12 = (n12 + 255) / 256;
    hist2_kernel<<<nb12, 256, 0, stream>>>(coords1, n1, coords2, n2, pos);
    scan_kernel<<<1, SCAN_T, 0, stream>>>(pos);
    scatter2_kernel<<<nb12, 256, 0, stream>>>(coords1, n1, coords2, n2, pos, recs);
    fuse_kernel<<<NBIN, 256, 0, stream>>>(feats1, feats2, recs, pos, out);
}

// Round 8
// 183.750 us; speedup vs baseline: 1.4156x; 1.3164x over previous
//
#include <hip/hip_runtime.h>
#include <float.h>

// Grid dims from the reference
#define BDIM 4
#define ZDIM 6
#define YDIM 200
#define XDIM 176
#define CDIM 64
#define KSLOTS (BDIM * ZDIM * YDIM * XDIM)  // 844800
#define BINV 64                              // voxels per bin
#define NBIN (KSLOTS / BINV)                 // 13200
#define CAP1 64                              // fixed slots/bin, set1 (mean ~15, +12 sigma)
#define CAP2 192                             // fixed slots/bin, set2 (mean ~61, +17 sigma)
#define CAPT (CAP1 + CAP2)                   // 256 recs per bin
#define OVFCAP 16384

typedef float f32x4 __attribute__((ext_vector_type(4)));

__device__ __forceinline__ int voxel_key4(const int4 c) {
    return ((c.x * ZDIM + c.y) * YDIM + c.z) * XDIM + c.w;
}
// monotonic float<->uint order encoding; 0u = "empty" sentinel (below all reals)
__device__ __forceinline__ unsigned ord_enc(float f) {
    unsigned u = __float_as_uint(f);
    return (u & 0x80000000u) ? ~u : (u | 0x80000000u);
}
__device__ __forceinline__ float ord_dec(unsigned u) {
    return (u & 0x80000000u) ? __uint_as_float(u & 0x7FFFFFFFu)
                             : __uint_as_float(~u);
}

// ---------------- single-pass fixed-capacity scatter ----------------
// recs[bin*CAPT + 0..CAP1)   = set1 records (point<<6 | local_voxel)
// recs[bin*CAPT + CAP1..CAPT)= set2 records
// Overflow (statistically never): record -> ovf list, bin -> dirty list;
// fixup_kernel recomputes dirty bins exactly.
__global__ void scatter_fixed_kernel(const int* __restrict__ c1, int n1,
                                     const int* __restrict__ c2, int n2,
                                     int* __restrict__ cnt, int* __restrict__ dirty,
                                     int* __restrict__ ctr, int* __restrict__ dlist,
                                     int* __restrict__ ovf, int* __restrict__ recs) {
    int i = blockIdx.x * blockDim.x + threadIdx.x;
    int rec = 0, cslot = 0, bin = 0, capv = 0, rbase = 0;
    bool valid = false;
    if (i < n1) {
        int4 cc = *reinterpret_cast<const int4*>(c1 + (long long)i * 4);
        int key = voxel_key4(cc);
        bin = key >> 6;
        rec = (i << 6) | (key & 63);
        cslot = 2 * bin;     capv = CAP1; rbase = bin * CAPT;        valid = true;
    } else if (i < n1 + n2) {
        int j = i - n1;
        int4 cc = *reinterpret_cast<const int4*>(c2 + (long long)j * 4);
        int key = voxel_key4(cc);
        bin = key >> 6;
        rec = (j << 6) | (key & 63);
        cslot = 2 * bin + 1; capv = CAP2; rbase = bin * CAPT + CAP1; valid = true;
    }
    if (valid) {
        int c = atomicAdd(&cnt[cslot], 1);
        if (c < capv) {
            recs[rbase + c] = rec;
        } else {
            int o = atomicAdd(&ctr[1], 1);
            if (o < OVFCAP) { ovf[2 * o] = rec; ovf[2 * o + 1] = cslot; }
            if (atomicExch(&dirty[bin], 1) == 0) {
                int d = atomicAdd(&ctr[0], 1);
                dlist[d] = bin;
            }
        }
    }
}

// ---------------- fused bin-local accumulate ----------------
// One block per bin (64 voxels x 64 ch = 16KB LDS tile). Stage the bin's
// record lists in LDS; 8 groups x 32 lanes issue 16 independent global
// dword loads per iteration (8 points x 2 half-rows) before any LDS atomic.
__global__ __launch_bounds__(256) void fuse_kernel(
        const float* __restrict__ f1, const float* __restrict__ f2,
        const int* __restrict__ recs, const int* __restrict__ cnt,
        float* __restrict__ out) {
    __shared__ unsigned acc[BINV * CDIM];   // 16 KB (encoded uints, then floats)
    __shared__ int rl1[CAP1];
    __shared__ int rl2[CAP2];
    int b = blockIdx.x;
    int t = threadIdx.x;
    int c1 = cnt[2 * b], c2 = cnt[2 * b + 1];
    int ns1 = min(c1, CAP1), ns2 = min(c2, CAP2);
    const int rb = b * CAPT;

    #pragma unroll
    for (int k = 0; k < 16; ++k) acc[t + k * 256] = 0u;  // 0 = empty sentinel
    for (int i = t; i < ns2; i += 256) rl2[i] = recs[rb + CAP1 + i];
    for (int i = t; i < ns1; i += 256) rl1[i] = recs[rb + i];
    __syncthreads();

    int lane = t & 31;   // channel lane (covers ch lane and lane+32)
    int grp  = t >> 5;   // 8 point-groups

    // ---- set2: scatter-max into LDS, 8 points/group/iter ----
    for (int base = 0; base < ns2; base += 64) {
        int i0 = base + grp * 8;
        int last = ns2 - 1;
        int rr[8]; float lo[8], hi[8];
        #pragma unroll
        for (int k = 0; k < 8; ++k) rr[k] = rl2[min(i0 + k, last)];
        #pragma unroll
        for (int k = 0; k < 8; ++k) {
            const float* p = f2 + (long long)(rr[k] >> 6) * CDIM;
            lo[k] = p[lane];
            hi[k] = p[lane + 32];
        }
        #pragma unroll
        for (int k = 0; k < 8; ++k) {
            if (i0 + k < ns2) {
                int lv = (rr[k] & 63) * CDIM;
                atomicMax(&acc[lv + lane],      ord_enc(lo[k]));
                atomicMax(&acc[lv + lane + 32], ord_enc(hi[k]));
            }
        }
    }
    __syncthreads();

    // in-place decode: encoded uint -> float bits (0u -> 0.0f)
    #pragma unroll
    for (int k = 0; k < 16; ++k) {
        int w = t + k * 256;
        unsigned u = acc[w];
        acc[w] = __float_as_uint((u == 0u) ? 0.f : ord_dec(u));
    }
    __syncthreads();

    float* facc = (float*)acc;

    // ---- set1: scatter-add onto decoded max, 4 points/group/iter ----
    for (int base = 0; base < ns1; base += 32) {
        int i0 = base + grp * 4;
        int last = ns1 - 1;
        int rr[4]; float lo[4], hi[4];
        #pragma unroll
        for (int k = 0; k < 4; ++k) rr[k] = rl1[min(i0 + k, last)];
        #pragma unroll
        for (int k = 0; k < 4; ++k) {
            const float* p = f1 + (long long)(rr[k] >> 6) * CDIM;
            lo[k] = p[lane];
            hi[k] = p[lane + 32];
        }
        #pragma unroll
        for (int k = 0; k < 4; ++k) {
            if (i0 + k < ns1) {
                int lv = (rr[k] & 63) * CDIM;
                atomicAdd(&facc[lv + lane],      lo[k]);
                atomicAdd(&facc[lv + lane + 32], hi[k]);
            }
        }
    }
    __syncthreads();

    // ---- writeout: contiguous 16KB, full-line nt stores ----
    float* ob = out + (long long)b * (BINV * CDIM);
    #pragma unroll
    for (int k = 0; k < 4; ++k) {
        int w = k * 1024 + t * 4;
        f32x4 val = *(f32x4*)&facc[w];
        __builtin_nontemporal_store(val, (f32x4*)(ob + w));
    }
}

// ---------------- dirty-bin exact recompute (statistically never runs) ----
__global__ __launch_bounds__(256) void fixup_kernel(
        const float* __restrict__ f1, const float* __restrict__ f2,
        const int* __restrict__ recs, const int* __restrict__ cnt,
        const int* __restrict__ ctr, const int* __restrict__ dlist,
        const int* __restrict__ ovf, float* __restrict__ out) {
    __shared__ unsigned acc[BINV * CDIM];
    int nd = ctr[0];
    int novf = min(ctr[1], OVFCAP);
    int t = threadIdx.x;
    int lane = t & 31, grp = t >> 5;
    for (int d = blockIdx.x; d < nd; d += gridDim.x) {
        int b = dlist[d];
        int c1 = cnt[2 * b], c2 = cnt[2 * b + 1];
        int ns1 = min(c1, CAP1), ns2 = min(c2, CAP2);
        #pragma unroll
        for (int k = 0; k < 16; ++k) acc[t + k * 256] = 0u;
        __syncthreads();
        for (int i = grp; i < ns2; i += 8) {
            int rec = recs[b * CAPT + CAP1 + i];
            const float* p = f2 + (long long)(rec >> 6) * CDIM;
            int lv = (rec & 63) * CDIM;
            atomicMax(&acc[lv + lane],      ord_enc(p[lane]));
            atomicMax(&acc[lv + lane + 32], ord_enc(p[lane + 32]));
        }
        for (int i = grp; i < novf; i += 8) {
            if (ovf[2 * i + 1] == 2 * b + 1) {
                int rec = ovf[2 * i];
                const float* p = f2 + (long long)(rec >> 6) * CDIM;
                int lv = (rec & 63) * CDIM;
                atomicMax(&acc[lv + lane],      ord_enc(p[lane]));
                atomicMax(&acc[lv + lane + 32], ord_enc(p[lane + 32]));
            }
        }
        __syncthreads();
        #pragma unroll
        for (int k = 0; k < 16; ++k) {
            int w = t + k * 256;
            unsigned u = acc[w];
            acc[w] = __float_as_uint((u == 0u) ? 0.f : ord_dec(u));
        }
        __syncthreads();
        float* facc = (float*)acc;
        for (int i = grp; i < ns1; i += 8) {
            int rec = recs[b * CAPT + i];
            const float* p = f1 + (long long)(rec >> 6) * CDIM;
            int lv = (rec & 63) * CDIM;
            atomicAdd(&facc[lv + lane],      p[lane]);
            atomicAdd(&facc[lv + lane + 32], p[lane + 32]);
        }
        for (int i = grp; i < novf; i += 8) {
            if (ovf[2 * i + 1] == 2 * b) {
                int rec = ovf[2 * i];
                const float* p = f1 + (long long)(rec >> 6) * CDIM;
                int lv = (rec & 63) * CDIM;
                atomicAdd(&facc[lv + lane],      p[lane]);
                atomicAdd(&facc[lv + lane + 32], p[lane + 32]);
            }
        }
        __syncthreads();
        float* ob = out + (long long)b * (BINV * CDIM);
        #pragma unroll
        for (int k = 0; k < 4; ++k) {
            int w = k * 1024 + t * 4;
            *(f32x4*)(ob + w) = *(f32x4*)&facc[w];
        }
        __syncthreads();
    }
}

// ---------------- fallback (atomic path, used only if ws too small) ----------

__global__ void fb_scatter_max(const float* __restrict__ feats, const int* __restrict__ coords,
                               unsigned* __restrict__ out, int npts) {
    long long i = (long long)blockIdx.x * blockDim.x + threadIdx.x;
    if (i >= (long long)npts * (CDIM / 4)) return;
    int pt = (int)(i >> 4), c4 = (int)(i & 15);
    int4 cc = *reinterpret_cast<const int4*>(coords + (long long)pt * 4);
    int key = voxel_key4(cc);
    float4 f = *reinterpret_cast<const float4*>(feats + (long long)pt * CDIM + c4 * 4);
    unsigned* dst = out + (long long)key * CDIM + c4 * 4;
    atomicMax(dst + 0, ord_enc(f.x));
    atomicMax(dst + 1, ord_enc(f.y));
    atomicMax(dst + 2, ord_enc(f.z));
    atomicMax(dst + 3, ord_enc(f.w));
}
__global__ void fb_decode(unsigned* __restrict__ buf, long long n4) {
    long long i = (long long)blockIdx.x * blockDim.x + threadIdx.x;
    if (i >= n4) return;
    uint4 u = reinterpret_cast<const uint4*>(buf)[i];
    float4 f;
    f.x = (u.x == 0u) ? 0.f : ord_dec(u.x);
    f.y = (u.y == 0u) ? 0.f : ord_dec(u.y);
    f.z = (u.z == 0u) ? 0.f : ord_dec(u.z);
    f.w = (u.w == 0u) ? 0.f : ord_dec(u.w);
    reinterpret_cast<float4*>(buf)[i] = f;
}
__global__ void fb_scatter_add(const float* __restrict__ feats, const int* __restrict__ coords,
                               float* __restrict__ out, int npts) {
    long long i = (long long)blockIdx.x * blockDim.x + threadIdx.x;
    if (i >= (long long)npts * (CDIM / 4)) return;
    int pt = (int)(i >> 4), c4 = (int)(i & 15);
    int4 cc = *reinterpret_cast<const int4*>(coords + (long long)pt * 4);
    int key = voxel_key4(cc);
    float4 f = *reinterpret_cast<const float4*>(feats + (long long)pt * CDIM + c4 * 4);
    float* dst = out + (long long)key * CDIM + c4 * 4;
    atomicAdd(dst + 0, f.x); atomicAdd(dst + 1, f.y);
    atomicAdd(dst + 2, f.z); atomicAdd(dst + 3, f.w);
}

extern "C" void kernel_launch(void* const* d_in, const int* in_sizes, int n_in,
                              void* d_out, int out_size, void* d_ws, size_t ws_size,
                              hipStream_t stream) {
    const float* feats1 = (const float*)d_in[0];
    const int*   coords1 = (const int*)d_in[1];
    const float* feats2 = (const float*)d_in[2];
    const int*   coords2 = (const int*)d_in[3];
    float* out = (float*)d_out;

    const int n1 = in_sizes[1] / 4;
    const int n2 = in_sizes[3] / 4;
    const int n12 = n1 + n2;
    const long long kc = (long long)KSLOTS * CDIM;

    // ws layout (ints): cnt[2*NBIN] | dirty[NBIN] | ctr[2] | dlist[NBIN] |
    //                   ovf[2*OVFCAP] | recs[NBIN*CAPT]
    const size_t needed = ((size_t)3 * NBIN + 2 + NBIN + 2 * OVFCAP
                           + (size_t)NBIN * CAPT) * sizeof(int);
    if (ws_size < needed) {
        hipMemsetAsync(d_out, 0, kc * sizeof(float), stream);
        long long t2 = (long long)n2 * (CDIM / 4);
        fb_scatter_max<<<(int)((t2 + 255) / 256), 256, 0, stream>>>(feats2, coords2,
                                                                    (unsigned*)out, n2);
        long long q = kc / 4;
        fb_decode<<<(int)((q + 255) / 256), 256, 0, stream>>>((unsigned*)out, q);
        long long t1 = (long long)n1 * (CDIM / 4);
        fb_scatter_add<<<(int)((t1 + 255) / 256), 256, 0, stream>>>(feats1, coords1, out, n1);
        return;
    }

    int* cnt   = (int*)d_ws;
    int* dirty = cnt + 2 * NBIN;
    int* ctr   = dirty + NBIN;
    int* dlist = ctr + 2;
    int* ovf   = dlist + NBIN;
    int* recs  = ovf + 2 * OVFCAP;

    // zero cnt + dirty + ctr (contiguous prefix, 158 KB)
    hipMemsetAsync(cnt, 0, ((size_t)3 * NBIN + 2) * sizeof(int), stream);

    int nb12 = (n12 + 255) / 256;
    scatter_fixed_kernel<<<nb12, 256, 0, stream>>>(coords1, n1, coords2, n2,
                                                   cnt, dirty, ctr, dlist, ovf, recs);
    fuse_kernel<<<NBIN, 256, 0, stream>>>(feats1, feats2, recs, cnt, out);
    fixup_kernel<<<64, 256, 0, stream>>>(feats1, feats2, recs, cnt, ctr, dlist, ovf, out);
}